// Round 5
// baseline (589.083 us; speedup 1.0000x reference)
//
#include <hip/hip_runtime.h>

#define BATCH 64
#define NIN 1024
#define IVL 64
#define ONUM 64
#define LVL 32
#define OLSZ 2048  // ONUM*LVL

typedef __attribute__((ext_vector_type(4))) float f32x4;
typedef __attribute__((ext_vector_type(8))) short short8;

static __device__ __forceinline__ unsigned short f2bf(float f) {
  unsigned u = __builtin_bit_cast(unsigned, f);
  u += 0x7fffu + ((u >> 16) & 1u);
  return (unsigned short)(u >> 16);
}
static __device__ __forceinline__ float bf2f_lo(unsigned x) {
  return __builtin_bit_cast(float, x << 16);
}
static __device__ __forceinline__ float bf2f_hi(unsigned x) {
  return __builtin_bit_cast(float, x & 0xffff0000u);
}

// K1: u_hat[b,n,o,l] = sum_i u[b,n,i]*W[n,o,l,i] + bias[n,o,l], stored bf16.
// Grid (n, eighth). Wave owns 4 tiles of 16 cols. W loads issued as ONE
// asm-volatile burst (16x global_load_dwordx4 = 16KB/wave in flight) that
// the compiler cannot sink. u-staging + __syncthreads overlaps the latency.
__global__ __launch_bounds__(256) void k_gemm(
    const float* __restrict__ u, const float* __restrict__ w,
    const float* __restrict__ bias, unsigned short* __restrict__ uhat) {
  const int n = blockIdx.x;
  const int eighth = blockIdx.y;
  __shared__ __align__(16) unsigned short a_lds[64 * 72];
  const int t = threadIdx.x;
  const int lane = t & 63;
  const int wave = t >> 6;
  const int row16 = lane & 15;
  const int quad = lane >> 4;

  const int cbase = eighth * 256 + wave * 64;  // 4 tiles of 16 cols per wave
  const float* wp =
      w + (size_t)n * (OLSZ * IVL) + (size_t)(cbase + row16) * IVL + quad * 8;
  const float* p0 = wp;                 // tile 0 (cols +0..15)
  const float* p1 = wp + 16 * IVL;      // tile 1
  const float* p2 = wp + 32 * IVL;      // tile 2
  const float* p3 = wp + 48 * IVL;      // tile 3

  // ---- unsinkable load burst: 16 x dwordx4 (256 floats of W per lane)
  f32x4 wv0, wv1, wv2, wv3, wv4, wv5, wv6, wv7;
  f32x4 wv8, wv9, wv10, wv11, wv12, wv13, wv14, wv15;
  asm volatile(
      "global_load_dwordx4 %[w0], %[p0], off\n\t"
      "global_load_dwordx4 %[w1], %[p0], off offset:16\n\t"
      "global_load_dwordx4 %[w2], %[p0], off offset:128\n\t"
      "global_load_dwordx4 %[w3], %[p0], off offset:144\n\t"
      "global_load_dwordx4 %[w4], %[p1], off\n\t"
      "global_load_dwordx4 %[w5], %[p1], off offset:16\n\t"
      "global_load_dwordx4 %[w6], %[p1], off offset:128\n\t"
      "global_load_dwordx4 %[w7], %[p1], off offset:144\n\t"
      "global_load_dwordx4 %[w8], %[p2], off\n\t"
      "global_load_dwordx4 %[w9], %[p2], off offset:16\n\t"
      "global_load_dwordx4 %[w10], %[p2], off offset:128\n\t"
      "global_load_dwordx4 %[w11], %[p2], off offset:144\n\t"
      "global_load_dwordx4 %[w12], %[p3], off\n\t"
      "global_load_dwordx4 %[w13], %[p3], off offset:16\n\t"
      "global_load_dwordx4 %[w14], %[p3], off offset:128\n\t"
      "global_load_dwordx4 %[w15], %[p3], off offset:144\n\t"
      : [w0] "=&v"(wv0), [w1] "=&v"(wv1), [w2] "=&v"(wv2), [w3] "=&v"(wv3),
        [w4] "=&v"(wv4), [w5] "=&v"(wv5), [w6] "=&v"(wv6), [w7] "=&v"(wv7),
        [w8] "=&v"(wv8), [w9] "=&v"(wv9), [w10] "=&v"(wv10),
        [w11] "=&v"(wv11), [w12] "=&v"(wv12), [w13] "=&v"(wv13),
        [w14] "=&v"(wv14), [w15] "=&v"(wv15)
      : [p0] "v"(p0), [p1] "v"(p1), [p2] "v"(p2), [p3] "v"(p3)
      : "memory");

  // bias (small, L2-hot; ordinary loads)
  float4 bv[4];
#pragma unroll
  for (int tile = 0; tile < 4; ++tile)
    bv[tile] = *(const float4*)(bias + (size_t)n * OLSZ + cbase + tile * 16 +
                                quad * 4);

  // ---- stage u[:, n, :] as bf16 into LDS (overlaps W latency)
  {
    const int b = t >> 2;
    const int i0 = (t & 3) * 16;
    const float* src = u + (size_t)b * (NIN * IVL) + (size_t)n * IVL + i0;
    unsigned short* dst = a_lds + b * 72 + i0;
#pragma unroll
    for (int q = 0; q < 4; ++q) {
      float4 v = *(const float4*)(src + q * 4);
      dst[q * 4 + 0] = f2bf(v.x);
      dst[q * 4 + 1] = f2bf(v.y);
      dst[q * 4 + 2] = f2bf(v.z);
      dst[q * 4 + 3] = f2bf(v.w);
    }
  }
  __syncthreads();
  asm volatile("s_waitcnt vmcnt(0)" ::: "memory");
  __builtin_amdgcn_sched_barrier(0);

  // ---- u fragments, read once, kept in registers
  short8 uf[4][2];
#pragma unroll
  for (int bt = 0; bt < 4; ++bt) {
#pragma unroll
    for (int ks = 0; ks < 2; ++ks) {
      uf[bt][ks] =
          *(const short8*)(a_lds + (bt * 16 + row16) * 72 + ks * 32 + quad * 8);
    }
  }

  unsigned short* ubase =
      uhat + ((size_t)row16 * NIN + n) * OLSZ + cbase + quad * 4;

  const f32x4 wvs[16] = {wv0, wv1, wv2,  wv3,  wv4,  wv5,  wv6,  wv7,
                         wv8, wv9, wv10, wv11, wv12, wv13, wv14, wv15};
#pragma unroll
  for (int tile = 0; tile < 4; ++tile) {
    const f32x4 cA0 = wvs[tile * 4 + 0];
    const f32x4 cA1 = wvs[tile * 4 + 1];
    const f32x4 cA2 = wvs[tile * 4 + 2];
    const f32x4 cA3 = wvs[tile * 4 + 3];
    short8 wf0, wf1;
    wf0[0] = (short)f2bf(cA0[0]); wf0[1] = (short)f2bf(cA0[1]);
    wf0[2] = (short)f2bf(cA0[2]); wf0[3] = (short)f2bf(cA0[3]);
    wf0[4] = (short)f2bf(cA1[0]); wf0[5] = (short)f2bf(cA1[1]);
    wf0[6] = (short)f2bf(cA1[2]); wf0[7] = (short)f2bf(cA1[3]);
    wf1[0] = (short)f2bf(cA2[0]); wf1[1] = (short)f2bf(cA2[1]);
    wf1[2] = (short)f2bf(cA2[2]); wf1[3] = (short)f2bf(cA2[3]);
    wf1[4] = (short)f2bf(cA3[0]); wf1[5] = (short)f2bf(cA3[1]);
    wf1[6] = (short)f2bf(cA3[2]); wf1[7] = (short)f2bf(cA3[3]);

    f32x4 acc[4];
#pragma unroll
    for (int bt = 0; bt < 4; ++bt) acc[bt] = (f32x4){0.f, 0.f, 0.f, 0.f};
#pragma unroll
    for (int bt = 0; bt < 4; ++bt) {
      acc[bt] = __builtin_amdgcn_mfma_f32_16x16x32_bf16(wf0, uf[bt][0],
                                                        acc[bt], 0, 0, 0);
      acc[bt] = __builtin_amdgcn_mfma_f32_16x16x32_bf16(wf1, uf[bt][1],
                                                        acc[bt], 0, 0, 0);
    }
#pragma unroll
    for (int bt = 0; bt < 4; ++bt) {
      unsigned h0 = f2bf(acc[bt][0] + bv[tile].x);
      unsigned h1 = f2bf(acc[bt][1] + bv[tile].y);
      unsigned h2 = f2bf(acc[bt][2] + bv[tile].z);
      unsigned h3 = f2bf(acc[bt][3] + bv[tile].w);
      uint2 pk = make_uint2(h0 | (h1 << 16), h2 | (h3 << 16));
      *(uint2*)(ubase + (size_t)bt * 16 * NIN * OLSZ + tile * 16) = pk;
    }
  }
}

// K2: s1[b,ol] = sum_n uhat[b,n,ol]. Dense coalesced.
__global__ __launch_bounds__(256) void k_sum_n(
    const unsigned short* __restrict__ uhat, float* __restrict__ s1) {
  const int b = blockIdx.x >> 5;
  const int chunk = blockIdx.x & 31;
  const int t = threadIdx.x;
  const unsigned short* base =
      uhat + ((size_t)b * NIN + (size_t)chunk * 32) * OLSZ + t * 8;
  float acc[8];
#pragma unroll
  for (int j = 0; j < 8; ++j) acc[j] = 0.f;
#pragma unroll 4
  for (int k = 0; k < 32; ++k) {
    uint4 p = *(const uint4*)(base + (size_t)k * OLSZ);
    unsigned xs[4] = {p.x, p.y, p.z, p.w};
#pragma unroll
    for (int h = 0; h < 4; ++h) {
      acc[2 * h] += bf2f_lo(xs[h]);
      acc[2 * h + 1] += bf2f_hi(xs[h]);
    }
  }
  float* s = s1 + (size_t)b * OLSZ + t * 8;
#pragma unroll
  for (int j = 0; j < 8; ++j) atomicAdd(s + j, acc[j]);
}

// K3/K4: one routing iteration, dense-coalesced + software pipelined.
// Element f = q*512 + lane*8 + j  <->  o = 16q + lane/4, l = (lane%4)*8 + j.
__global__ __launch_bounds__(256) void k_route(
    const unsigned short* __restrict__ uhat, const float* __restrict__ sv,
    float scale, float* __restrict__ b1, int add_b1,
    float* __restrict__ sout) {
  const int b = blockIdx.x >> 5;
  const int chunk = blockIdx.x & 31;
  const int t = threadIdx.x;
  const int lane = t & 63;
  const int wave = t >> 6;
  const int g = lane >> 2;
  __shared__ float red[4][OLSZ];  // 32 KB

  float v[4][8];
#pragma unroll
  for (int q = 0; q < 4; ++q) {
    const float* svp = sv + (size_t)b * OLSZ + q * 512 + lane * 8;
    float4 a0 = *(const float4*)svp;
    float4 a1 = *(const float4*)(svp + 4);
    v[q][0] = a0.x * scale; v[q][1] = a0.y * scale;
    v[q][2] = a0.z * scale; v[q][3] = a0.w * scale;
    v[q][4] = a1.x * scale; v[q][5] = a1.y * scale;
    v[q][6] = a1.z * scale; v[q][7] = a1.w * scale;
    float p = 0.f;
#pragma unroll
    for (int j = 0; j < 8; ++j) p = fmaf(v[q][j], v[q][j], p);
    p += __shfl_xor(p, 1);
    p += __shfl_xor(p, 2);
    float f = p / ((1.f + p) * (sqrtf(p) + 1e-5f));
#pragma unroll
    for (int j = 0; j < 8; ++j) v[q][j] *= f;
  }

  float racc[4][8];
#pragma unroll
  for (int q = 0; q < 4; ++q)
#pragma unroll
    for (int j = 0; j < 8; ++j) racc[q][j] = 0.f;

  const int n0 = chunk * 32 + wave * 8;
  const unsigned short* ub = uhat + ((size_t)b * NIN + n0) * OLSZ + lane * 8;

  uint4 pA[4], pB[4];
#pragma unroll
  for (int q = 0; q < 4; ++q) pA[q] = *(const uint4*)(ub + q * 512);

  auto process = [&](const uint4(&pk)[4], int k) {
    const int n = n0 + k;
    const size_t bbase = ((size_t)b * NIN + n) * ONUM + g;
    float b1v[4];
    if (add_b1) {
#pragma unroll
      for (int q = 0; q < 4; ++q) b1v[q] = b1[bbase + 16 * q];
    }
    float ud[4][8];
    float d[4];
#pragma unroll
    for (int q = 0; q < 4; ++q) {
      unsigned xs[4] = {pk[q].x, pk[q].y, pk[q].z, pk[q].w};
#pragma unroll
      for (int h = 0; h < 4; ++h) {
        ud[q][2 * h] = bf2f_lo(xs[h]);
        ud[q][2 * h + 1] = bf2f_hi(xs[h]);
      }
      float p = 0.f;
#pragma unroll
      for (int j = 0; j < 8; ++j) p = fmaf(ud[q][j], v[q][j], p);
      p += __shfl_xor(p, 1);
      p += __shfl_xor(p, 2);
      d[q] = p;
    }
    float bno[4];
    if (add_b1) {
#pragma unroll
      for (int q = 0; q < 4; ++q) bno[q] = d[q] + b1v[q];
    } else {
#pragma unroll
      for (int q = 0; q < 4; ++q) bno[q] = d[q];
      if ((lane & 3) == 0) {
#pragma unroll
        for (int q = 0; q < 4; ++q) b1[bbase + 16 * q] = d[q];
      }
    }
    float m = fmaxf(fmaxf(bno[0], bno[1]), fmaxf(bno[2], bno[3]));
#pragma unroll
    for (int dl = 4; dl < 64; dl <<= 1) m = fmaxf(m, __shfl_xor(m, dl));
    float e0 = __expf(bno[0] - m);
    float e1 = __expf(bno[1] - m);
    float e2 = __expf(bno[2] - m);
    float e3 = __expf(bno[3] - m);
    float ls = (e0 + e1) + (e2 + e3);
#pragma unroll
    for (int dl = 4; dl < 64; dl <<= 1) ls += __shfl_xor(ls, dl);
    float inv = 1.0f / ls;
    float c[4] = {e0 * inv, e1 * inv, e2 * inv, e3 * inv};
#pragma unroll
    for (int q = 0; q < 4; ++q) {
#pragma unroll
      for (int j = 0; j < 8; ++j)
        racc[q][j] = fmaf(c[q], ud[q][j], racc[q][j]);
    }
  };

#pragma unroll
  for (int kk = 0; kk < 4; ++kk) {
    {
#pragma unroll
      for (int q = 0; q < 4; ++q)
        pB[q] = *(const uint4*)(ub + (size_t)(2 * kk + 1) * OLSZ + q * 512);
    }
    process(pA, 2 * kk);
    if (2 * kk + 2 < 8) {
#pragma unroll
      for (int q = 0; q < 4; ++q)
        pA[q] = *(const uint4*)(ub + (size_t)(2 * kk + 2) * OLSZ + q * 512);
    }
    process(pB, 2 * kk + 1);
  }

#pragma unroll
  for (int q = 0; q < 4; ++q) {
    float* dst = &red[wave][q * 512 + lane * 8];
    *(float4*)(dst) =
        make_float4(racc[q][0], racc[q][1], racc[q][2], racc[q][3]);
    *(float4*)(dst + 4) =
        make_float4(racc[q][4], racc[q][5], racc[q][6], racc[q][7]);
  }
  __syncthreads();
  float* so = sout + (size_t)b * OLSZ;
#pragma unroll
  for (int j = 0; j < 8; ++j) {
    const int idx = t + 256 * j;
    float s = (red[0][idx] + red[1][idx]) + (red[2][idx] + red[3][idx]);
    atomicAdd(so + idx, s);
  }
}

// K5: out = squash(s3)
__global__ __launch_bounds__(256) void k_final(const float* __restrict__ s3,
                                               float* __restrict__ out) {
  const int b = blockIdx.x;
  const int t = threadIdx.x;
  __shared__ float norm2[64];
  if (t < 64) norm2[t] = 0.f;
  __syncthreads();
  float scv[8];
#pragma unroll
  for (int k = 0; k < 8; ++k) {
    int idx = t + k * 256;
    float sc = s3[b * OLSZ + idx];
    scv[k] = sc;
    atomicAdd(&norm2[idx >> 5], sc * sc);
  }
  __syncthreads();
#pragma unroll
  for (int k = 0; k < 8; ++k) {
    int idx = t + k * 256;
    int o = idx >> 5;
    float n2 = norm2[o];
    float f = n2 / ((1.f + n2) * (sqrtf(n2) + 1e-5f));
    out[b * OLSZ + idx] = scv[k] * f;
  }
}

extern "C" void kernel_launch(void* const* d_in, const int* in_sizes, int n_in,
                              void* d_out, int out_size, void* d_ws,
                              size_t ws_size, hipStream_t stream) {
  const float* u = (const float*)d_in[0];
  const float* w = (const float*)d_in[1];
  const float* bias = (const float*)d_in[2];
  float* out = (float*)d_out;

  char* ws = (char*)d_ws;
  unsigned short* uhat = (unsigned short*)ws;                 // 268435456 B
  float* b1 = (float*)(ws + (size_t)268435456);               // 16777216 B
  float* s1 = (float*)(ws + (size_t)268435456 + 16777216);    // 524288 B
  float* s2 = s1 + 131072;                                    // 524288 B
  float* s3 = s2 + 131072;                                    // 524288 B

  hipMemsetAsync(s1, 0, 3 * 131072 * sizeof(float), stream);

  k_gemm<<<dim3(1024, 8), dim3(256), 0, stream>>>(u, w, bias, uhat);
  k_sum_n<<<dim3(2048), dim3(256), 0, stream>>>(uhat, s1);
  k_route<<<dim3(2048), dim3(256), 0, stream>>>(uhat, s1, 1.0f / 64.0f, b1, 0, s2);
  k_route<<<dim3(2048), dim3(256), 0, stream>>>(uhat, s2, 1.0f, b1, 1, s3);
  k_final<<<dim3(64), dim3(256), 0, stream>>>(s3, out);
}

// Round 6
// 492.061 us; speedup vs baseline: 1.1972x; 1.1972x over previous
//
#include <hip/hip_runtime.h>
#include <hip/hip_bf16.h>

#define BATCH 64
#define NIN 1024
#define IVL 64
#define ONUM 64
#define LVL 32
#define OLSZ 2048  // ONUM*LVL

typedef __attribute__((ext_vector_type(4))) float f32x4;
typedef __attribute__((ext_vector_type(8))) short short8;

static __device__ __forceinline__ unsigned short f2bf(float f) {
  unsigned u = __builtin_bit_cast(unsigned, f);
  u += 0x7fffu + ((u >> 16) & 1u);
  return (unsigned short)(u >> 16);
}
static __device__ __forceinline__ float bf2f_lo(unsigned x) {
  return __builtin_bit_cast(float, x << 16);
}
static __device__ __forceinline__ float bf2f_hi(unsigned x) {
  return __builtin_bit_cast(float, x & 0xffff0000u);
}

// 16-load W burst: 4 tile pointers, 4 dwordx4 each (256 B/lane).
#define W_BURST(W, q0, q1, q2, q3)                                       \
  asm volatile(                                                          \
      "global_load_dwordx4 %[w0], %[a0], off\n\t"                        \
      "global_load_dwordx4 %[w1], %[a0], off offset:16\n\t"              \
      "global_load_dwordx4 %[w2], %[a0], off offset:128\n\t"             \
      "global_load_dwordx4 %[w3], %[a0], off offset:144\n\t"             \
      "global_load_dwordx4 %[w4], %[a1], off\n\t"                        \
      "global_load_dwordx4 %[w5], %[a1], off offset:16\n\t"              \
      "global_load_dwordx4 %[w6], %[a1], off offset:128\n\t"             \
      "global_load_dwordx4 %[w7], %[a1], off offset:144\n\t"             \
      "global_load_dwordx4 %[w8], %[a2], off\n\t"                        \
      "global_load_dwordx4 %[w9], %[a2], off offset:16\n\t"              \
      "global_load_dwordx4 %[w10], %[a2], off offset:128\n\t"            \
      "global_load_dwordx4 %[w11], %[a2], off offset:144\n\t"            \
      "global_load_dwordx4 %[w12], %[a3], off\n\t"                       \
      "global_load_dwordx4 %[w13], %[a3], off offset:16\n\t"             \
      "global_load_dwordx4 %[w14], %[a3], off offset:128\n\t"            \
      "global_load_dwordx4 %[w15], %[a3], off offset:144\n\t"            \
      : [w0] "=&v"(W[0]), [w1] "=&v"(W[1]), [w2] "=&v"(W[2]),            \
        [w3] "=&v"(W[3]), [w4] "=&v"(W[4]), [w5] "=&v"(W[5]),            \
        [w6] "=&v"(W[6]), [w7] "=&v"(W[7]), [w8] "=&v"(W[8]),            \
        [w9] "=&v"(W[9]), [w10] "=&v"(W[10]), [w11] "=&v"(W[11]),        \
        [w12] "=&v"(W[12]), [w13] "=&v"(W[13]), [w14] "=&v"(W[14]),      \
        [w15] "=&v"(W[15])                                               \
      : [a0] "v"(q0), [a1] "v"(q1), [a2] "v"(q2), [a3] "v"(q3)           \
      : "memory")

// 16 packed stores: 4 row-base pointers (one per bt), tile offsets 0/32/64/96.
#define STORE16(P, s0, s1, s2, s3)                                       \
  asm volatile(                                                          \
      "global_store_dwordx2 %[a0], %[d0], off\n\t"                       \
      "global_store_dwordx2 %[a0], %[d1], off offset:32\n\t"             \
      "global_store_dwordx2 %[a0], %[d2], off offset:64\n\t"             \
      "global_store_dwordx2 %[a0], %[d3], off offset:96\n\t"             \
      "global_store_dwordx2 %[a1], %[d4], off\n\t"                       \
      "global_store_dwordx2 %[a1], %[d5], off offset:32\n\t"             \
      "global_store_dwordx2 %[a1], %[d6], off offset:64\n\t"             \
      "global_store_dwordx2 %[a1], %[d7], off offset:96\n\t"             \
      "global_store_dwordx2 %[a2], %[d8], off\n\t"                       \
      "global_store_dwordx2 %[a2], %[d9], off offset:32\n\t"             \
      "global_store_dwordx2 %[a2], %[d10], off offset:64\n\t"            \
      "global_store_dwordx2 %[a2], %[d11], off offset:96\n\t"            \
      "global_store_dwordx2 %[a3], %[d12], off\n\t"                      \
      "global_store_dwordx2 %[a3], %[d13], off offset:32\n\t"            \
      "global_store_dwordx2 %[a3], %[d14], off offset:64\n\t"            \
      "global_store_dwordx2 %[a3], %[d15], off offset:96\n\t"            \
      :: [a0] "v"(s0), [a1] "v"(s1), [a2] "v"(s2), [a3] "v"(s3),         \
         [d0] "v"(P[0]), [d1] "v"(P[1]), [d2] "v"(P[2]), [d3] "v"(P[3]), \
         [d4] "v"(P[4]), [d5] "v"(P[5]), [d6] "v"(P[6]), [d7] "v"(P[7]), \
         [d8] "v"(P[8]), [d9] "v"(P[9]), [d10] "v"(P[10]),               \
         [d11] "v"(P[11]), [d12] "v"(P[12]), [d13] "v"(P[13]),           \
         [d14] "v"(P[14]), [d15] "v"(P[15])                              \
      : "memory")

#define VMWAIT16                                        \
  do {                                                  \
    asm volatile("s_waitcnt vmcnt(16)" ::: "memory");   \
    __builtin_amdgcn_sched_barrier(0);                  \
  } while (0)
#define VMWAIT0                                         \
  do {                                                  \
    asm volatile("s_waitcnt vmcnt(0)" ::: "memory");    \
    __builtin_amdgcn_sched_barrier(0);                  \
  } while (0)

// K1: u_hat[b,n,o,l] = sum_i u[b,n,i]*W[n,o,l,i] + bias, stored bf16.
// Grid (n, half). Block loops 4 chunks of 256 cols, depth-2 pipelined:
// asm W-burst double buffer + counted vmcnt(16) + asm packed stores.
__global__ __launch_bounds__(256, 2) void k_gemm(
    const float* __restrict__ u, const float* __restrict__ w,
    const float* __restrict__ bias, unsigned short* __restrict__ uhat) {
  const int n = blockIdx.x;
  const int half = blockIdx.y;
  __shared__ __align__(16) unsigned short a_lds[64 * 72];
  __shared__ __align__(16) float bias_lds[1024];
  const int t = threadIdx.x;
  const int lane = t & 63;
  const int wave = t >> 6;
  const int row16 = lane & 15;
  const int quad = lane >> 4;

  // ---- prologue: stage u[:,n,:] (bf16) and bias[n, half-cols] into LDS
  {
    const int b = t >> 2;
    const int i0 = (t & 3) * 16;
    const float* src = u + (size_t)b * (NIN * IVL) + (size_t)n * IVL + i0;
    unsigned short* dst = a_lds + b * 72 + i0;
#pragma unroll
    for (int q = 0; q < 4; ++q) {
      float4 v = *(const float4*)(src + q * 4);
      dst[q * 4 + 0] = f2bf(v.x);
      dst[q * 4 + 1] = f2bf(v.y);
      dst[q * 4 + 2] = f2bf(v.z);
      dst[q * 4 + 3] = f2bf(v.w);
    }
    *(float4*)&bias_lds[t * 4] =
        *(const float4*)(bias + (size_t)n * OLSZ + half * 1024 + t * 4);
  }
  __syncthreads();

  // ---- u fragments, read once, kept in registers
  short8 uf[4][2];
#pragma unroll
  for (int bt = 0; bt < 4; ++bt) {
#pragma unroll
    for (int ks = 0; ks < 2; ++ks) {
      uf[bt][ks] =
          *(const short8*)(a_lds + (bt * 16 + row16) * 72 + ks * 32 + quad * 8);
    }
  }
  asm volatile("s_waitcnt lgkmcnt(0)" ::: "memory");
  __builtin_amdgcn_sched_barrier(0);

  // ---- base pointers
  const float* wp = w + (size_t)n * (OLSZ * IVL) +
                    (size_t)(half * 1024 + wave * 64 + row16) * IVL + quad * 8;
  const float* p0 = wp;                // tile 0
  const float* p1 = wp + 16 * IVL;     // tile 1
  const float* p2 = wp + 32 * IVL;     // tile 2
  const float* p3 = wp + 48 * IVL;     // tile 3
  const unsigned short* sb0 =
      uhat + ((size_t)(0 * 16 + row16) * NIN + n) * OLSZ + half * 1024 +
      wave * 64 + quad * 4;
  const unsigned short* sb1 = sb0 + (size_t)16 * NIN * OLSZ;
  const unsigned short* sb2 = sb0 + (size_t)32 * NIN * OLSZ;
  const unsigned short* sb3 = sb0 + (size_t)48 * NIN * OLSZ;

  f32x4 wvA[16], wvB[16];

#define COMPUTE_STORE(W, c)                                                   \
  do {                                                                        \
    uint2 pks[16];                                                            \
    _Pragma("unroll") for (int tile = 0; tile < 4; ++tile) {                  \
      const f32x4 A0 = W[tile * 4 + 0];                                       \
      const f32x4 A1 = W[tile * 4 + 1];                                       \
      const f32x4 A2 = W[tile * 4 + 2];                                       \
      const f32x4 A3 = W[tile * 4 + 3];                                       \
      short8 wf0, wf1;                                                        \
      wf0[0] = (short)f2bf(A0[0]); wf0[1] = (short)f2bf(A0[1]);               \
      wf0[2] = (short)f2bf(A0[2]); wf0[3] = (short)f2bf(A0[3]);               \
      wf0[4] = (short)f2bf(A1[0]); wf0[5] = (short)f2bf(A1[1]);               \
      wf0[6] = (short)f2bf(A1[2]); wf0[7] = (short)f2bf(A1[3]);               \
      wf1[0] = (short)f2bf(A2[0]); wf1[1] = (short)f2bf(A2[1]);               \
      wf1[2] = (short)f2bf(A2[2]); wf1[3] = (short)f2bf(A2[3]);               \
      wf1[4] = (short)f2bf(A3[0]); wf1[5] = (short)f2bf(A3[1]);               \
      wf1[6] = (short)f2bf(A3[2]); wf1[7] = (short)f2bf(A3[3]);               \
      float4 bf = *(const float4*)&bias_lds[(c) * 256 + wave * 64 +           \
                                            tile * 16 + quad * 4];            \
      f32x4 acc0 = (f32x4){0.f, 0.f, 0.f, 0.f};                               \
      f32x4 acc1 = acc0, acc2 = acc0, acc3 = acc0;                            \
      acc0 = __builtin_amdgcn_mfma_f32_16x16x32_bf16(wf0, uf[0][0], acc0, 0, 0, 0); \
      acc0 = __builtin_amdgcn_mfma_f32_16x16x32_bf16(wf1, uf[0][1], acc0, 0, 0, 0); \
      acc1 = __builtin_amdgcn_mfma_f32_16x16x32_bf16(wf0, uf[1][0], acc1, 0, 0, 0); \
      acc1 = __builtin_amdgcn_mfma_f32_16x16x32_bf16(wf1, uf[1][1], acc1, 0, 0, 0); \
      acc2 = __builtin_amdgcn_mfma_f32_16x16x32_bf16(wf0, uf[2][0], acc2, 0, 0, 0); \
      acc2 = __builtin_amdgcn_mfma_f32_16x16x32_bf16(wf1, uf[2][1], acc2, 0, 0, 0); \
      acc3 = __builtin_amdgcn_mfma_f32_16x16x32_bf16(wf0, uf[3][0], acc3, 0, 0, 0); \
      acc3 = __builtin_amdgcn_mfma_f32_16x16x32_bf16(wf1, uf[3][1], acc3, 0, 0, 0); \
      pks[0 * 4 + tile] = make_uint2(                                         \
          f2bf(acc0[0] + bf.x) | (f2bf(acc0[1] + bf.y) << 16),                \
          f2bf(acc0[2] + bf.z) | (f2bf(acc0[3] + bf.w) << 16));               \
      pks[1 * 4 + tile] = make_uint2(                                         \
          f2bf(acc1[0] + bf.x) | (f2bf(acc1[1] + bf.y) << 16),                \
          f2bf(acc1[2] + bf.z) | (f2bf(acc1[3] + bf.w) << 16));               \
      pks[2 * 4 + tile] = make_uint2(                                         \
          f2bf(acc2[0] + bf.x) | (f2bf(acc2[1] + bf.y) << 16),                \
          f2bf(acc2[2] + bf.z) | (f2bf(acc2[3] + bf.w) << 16));               \
      pks[3 * 4 + tile] = make_uint2(                                         \
          f2bf(acc3[0] + bf.x) | (f2bf(acc3[1] + bf.y) << 16),                \
          f2bf(acc3[2] + bf.z) | (f2bf(acc3[3] + bf.w) << 16));               \
    }                                                                         \
    const unsigned short* s0 = sb0 + (c) * 256;                               \
    const unsigned short* s1 = sb1 + (c) * 256;                               \
    const unsigned short* s2 = sb2 + (c) * 256;                               \
    const unsigned short* s3 = sb3 + (c) * 256;                               \
    STORE16(pks, s0, s1, s2, s3);                                             \
  } while (0)

  // ---- depth-2 pipelined chunk loop (4 chunks of 256 cols)
  W_BURST(wvA, p0, p1, p2, p3);
  W_BURST(wvB, p0 + 16384, p1 + 16384, p2 + 16384, p3 + 16384);
  VMWAIT16;
  COMPUTE_STORE(wvA, 0);
  W_BURST(wvA, p0 + 32768, p1 + 32768, p2 + 32768, p3 + 32768);
  VMWAIT16;
  COMPUTE_STORE(wvB, 1);
  W_BURST(wvB, p0 + 49152, p1 + 49152, p2 + 49152, p3 + 49152);
  VMWAIT16;
  COMPUTE_STORE(wvA, 2);
  VMWAIT0;
  COMPUTE_STORE(wvB, 3);
#undef COMPUTE_STORE
}

// K2: s1[b,ol] = sum_n uhat[b,n,ol]. Dense coalesced.
__global__ __launch_bounds__(256) void k_sum_n(
    const unsigned short* __restrict__ uhat, float* __restrict__ s1) {
  const int b = blockIdx.x >> 5;
  const int chunk = blockIdx.x & 31;
  const int t = threadIdx.x;
  const unsigned short* base =
      uhat + ((size_t)b * NIN + (size_t)chunk * 32) * OLSZ + t * 8;
  float acc[8];
#pragma unroll
  for (int j = 0; j < 8; ++j) acc[j] = 0.f;
#pragma unroll 4
  for (int k = 0; k < 32; ++k) {
    uint4 p = *(const uint4*)(base + (size_t)k * OLSZ);
    unsigned xs[4] = {p.x, p.y, p.z, p.w};
#pragma unroll
    for (int h = 0; h < 4; ++h) {
      acc[2 * h] += bf2f_lo(xs[h]);
      acc[2 * h + 1] += bf2f_hi(xs[h]);
    }
  }
  float* s = s1 + (size_t)b * OLSZ + t * 8;
#pragma unroll
  for (int j = 0; j < 8; ++j) atomicAdd(s + j, acc[j]);
}

// K3/K4: one routing iteration, dense-coalesced + software pipelined.
// Element f = q*512 + lane*8 + j  <->  o = 16q + lane/4, l = (lane%4)*8 + j.
__global__ __launch_bounds__(256) void k_route(
    const unsigned short* __restrict__ uhat, const float* __restrict__ sv,
    float scale, float* __restrict__ b1, int add_b1,
    float* __restrict__ sout) {
  const int b = blockIdx.x >> 5;
  const int chunk = blockIdx.x & 31;
  const int t = threadIdx.x;
  const int lane = t & 63;
  const int wave = t >> 6;
  const int g = lane >> 2;
  __shared__ float red[4][OLSZ];  // 32 KB

  float v[4][8];
#pragma unroll
  for (int q = 0; q < 4; ++q) {
    const float* svp = sv + (size_t)b * OLSZ + q * 512 + lane * 8;
    float4 a0 = *(const float4*)svp;
    float4 a1 = *(const float4*)(svp + 4);
    v[q][0] = a0.x * scale; v[q][1] = a0.y * scale;
    v[q][2] = a0.z * scale; v[q][3] = a0.w * scale;
    v[q][4] = a1.x * scale; v[q][5] = a1.y * scale;
    v[q][6] = a1.z * scale; v[q][7] = a1.w * scale;
    float p = 0.f;
#pragma unroll
    for (int j = 0; j < 8; ++j) p = fmaf(v[q][j], v[q][j], p);
    p += __shfl_xor(p, 1);
    p += __shfl_xor(p, 2);
    float f = p / ((1.f + p) * (sqrtf(p) + 1e-5f));
#pragma unroll
    for (int j = 0; j < 8; ++j) v[q][j] *= f;
  }

  float racc[4][8];
#pragma unroll
  for (int q = 0; q < 4; ++q)
#pragma unroll
    for (int j = 0; j < 8; ++j) racc[q][j] = 0.f;

  const int n0 = chunk * 32 + wave * 8;
  const unsigned short* ub = uhat + ((size_t)b * NIN + n0) * OLSZ + lane * 8;

  uint4 pA[4], pB[4];
#pragma unroll
  for (int q = 0; q < 4; ++q) pA[q] = *(const uint4*)(ub + q * 512);

  auto process = [&](const uint4(&pk)[4], int k) {
    const int n = n0 + k;
    const size_t bbase = ((size_t)b * NIN + n) * ONUM + g;
    float b1v[4];
    if (add_b1) {
#pragma unroll
      for (int q = 0; q < 4; ++q) b1v[q] = b1[bbase + 16 * q];
    }
    float ud[4][8];
    float d[4];
#pragma unroll
    for (int q = 0; q < 4; ++q) {
      unsigned xs[4] = {pk[q].x, pk[q].y, pk[q].z, pk[q].w};
#pragma unroll
      for (int h = 0; h < 4; ++h) {
        ud[q][2 * h] = bf2f_lo(xs[h]);
        ud[q][2 * h + 1] = bf2f_hi(xs[h]);
      }
      float p = 0.f;
#pragma unroll
      for (int j = 0; j < 8; ++j) p = fmaf(ud[q][j], v[q][j], p);
      p += __shfl_xor(p, 1);
      p += __shfl_xor(p, 2);
      d[q] = p;
    }
    float bno[4];
    if (add_b1) {
#pragma unroll
      for (int q = 0; q < 4; ++q) bno[q] = d[q] + b1v[q];
    } else {
#pragma unroll
      for (int q = 0; q < 4; ++q) bno[q] = d[q];
      if ((lane & 3) == 0) {
#pragma unroll
        for (int q = 0; q < 4; ++q) b1[bbase + 16 * q] = d[q];
      }
    }
    float m = fmaxf(fmaxf(bno[0], bno[1]), fmaxf(bno[2], bno[3]));
#pragma unroll
    for (int dl = 4; dl < 64; dl <<= 1) m = fmaxf(m, __shfl_xor(m, dl));
    float e0 = __expf(bno[0] - m);
    float e1 = __expf(bno[1] - m);
    float e2 = __expf(bno[2] - m);
    float e3 = __expf(bno[3] - m);
    float ls = (e0 + e1) + (e2 + e3);
#pragma unroll
    for (int dl = 4; dl < 64; dl <<= 1) ls += __shfl_xor(ls, dl);
    float inv = 1.0f / ls;
    float c[4] = {e0 * inv, e1 * inv, e2 * inv, e3 * inv};
#pragma unroll
    for (int q = 0; q < 4; ++q) {
#pragma unroll
      for (int j = 0; j < 8; ++j)
        racc[q][j] = fmaf(c[q], ud[q][j], racc[q][j]);
    }
  };

#pragma unroll
  for (int kk = 0; kk < 4; ++kk) {
    {
#pragma unroll
      for (int q = 0; q < 4; ++q)
        pB[q] = *(const uint4*)(ub + (size_t)(2 * kk + 1) * OLSZ + q * 512);
    }
    process(pA, 2 * kk);
    if (2 * kk + 2 < 8) {
#pragma unroll
      for (int q = 0; q < 4; ++q)
        pA[q] = *(const uint4*)(ub + (size_t)(2 * kk + 2) * OLSZ + q * 512);
    }
    process(pB, 2 * kk + 1);
  }

#pragma unroll
  for (int q = 0; q < 4; ++q) {
    float* dst = &red[wave][q * 512 + lane * 8];
    *(float4*)(dst) =
        make_float4(racc[q][0], racc[q][1], racc[q][2], racc[q][3]);
    *(float4*)(dst + 4) =
        make_float4(racc[q][4], racc[q][5], racc[q][6], racc[q][7]);
  }
  __syncthreads();
  float* so = sout + (size_t)b * OLSZ;
#pragma unroll
  for (int j = 0; j < 8; ++j) {
    const int idx = t + 256 * j;
    float s = (red[0][idx] + red[1][idx]) + (red[2][idx] + red[3][idx]);
    atomicAdd(so + idx, s);
  }
}

// K5: out = squash(s3)
__global__ __launch_bounds__(256) void k_final(const float* __restrict__ s3,
                                               float* __restrict__ out) {
  const int b = blockIdx.x;
  const int t = threadIdx.x;
  __shared__ float norm2[64];
  if (t < 64) norm2[t] = 0.f;
  __syncthreads();
  float scv[8];
#pragma unroll
  for (int k = 0; k < 8; ++k) {
    int idx = t + k * 256;
    float sc = s3[b * OLSZ + idx];
    scv[k] = sc;
    atomicAdd(&norm2[idx >> 5], sc * sc);
  }
  __syncthreads();
#pragma unroll
  for (int k = 0; k < 8; ++k) {
    int idx = t + k * 256;
    int o = idx >> 5;
    float n2 = norm2[o];
    float f = n2 / ((1.f + n2) * (sqrtf(n2) + 1e-5f));
    out[b * OLSZ + idx] = scv[k] * f;
  }
}

extern "C" void kernel_launch(void* const* d_in, const int* in_sizes, int n_in,
                              void* d_out, int out_size, void* d_ws,
                              size_t ws_size, hipStream_t stream) {
  const float* u = (const float*)d_in[0];
  const float* w = (const float*)d_in[1];
  const float* bias = (const float*)d_in[2];
  float* out = (float*)d_out;

  char* ws = (char*)d_ws;
  unsigned short* uhat = (unsigned short*)ws;                 // 268435456 B
  float* b1 = (float*)(ws + (size_t)268435456);               // 16777216 B
  float* s1 = (float*)(ws + (size_t)268435456 + 16777216);    // 524288 B
  float* s2 = s1 + 131072;                                    // 524288 B
  float* s3 = s2 + 131072;                                    // 524288 B

  hipMemsetAsync(s1, 0, 3 * 131072 * sizeof(float), stream);

  k_gemm<<<dim3(1024, 2), dim3(256), 0, stream>>>(u, w, bias, uhat);
  k_sum_n<<<dim3(2048), dim3(256), 0, stream>>>(uhat, s1);
  k_route<<<dim3(2048), dim3(256), 0, stream>>>(uhat, s1, 1.0f / 64.0f, b1, 0, s2);
  k_route<<<dim3(2048), dim3(256), 0, stream>>>(uhat, s2, 1.0f, b1, 1, s3);
  k_final<<<dim3(64), dim3(256), 0, stream>>>(s3, out);
}